// Round 13
// baseline (282.346 us; speedup 1.0000x reference)
//
#include <hip/hip_runtime.h>
#include <math.h>

#define KS 5

typedef __bf16 bf16x8 __attribute__((ext_vector_type(8)));
typedef float f32x4 __attribute__((ext_vector_type(4)));
typedef unsigned long long u64;

__device__ __forceinline__ unsigned int flipf(float f) {
    unsigned int b = __float_as_uint(f);
    return b ^ ((b >> 31) ? 0xFFFFFFFFu : 0x80000000u);
}
__device__ __forceinline__ float unflipf(unsigned int u) {
    unsigned int b = u ^ ((u >> 31) ? 0x80000000u : 0xFFFFFFFFu);
    return __uint_as_float(b);
}
__device__ __forceinline__ float pread(unsigned int u) {
    return (u == 0u) ? 0.f : unflipf(u);
}

__device__ __forceinline__ void basis1(float p, int& b, float& f) {
    float v = fminf(fmaxf(p, 0.f), 1.f) * (float)(KS - 1);
    float fl = fminf(floorf(v), (float)(KS - 2));
    b = (int)fl; f = v - fl;
}

// ---------- per-layer constants ----------
__device__ const int cE[5]     = {360000, 120000, 48000, 18000, 7200};
__device__ const int cN[5]     = {30000, 10000, 4000, 1500, 600};
__device__ const int cNB[5]    = {512, 469, 188, 71, 29};
__device__ const int cStart[5] = {0, 512, 981, 1169, 1240};
__device__ const int cBTend[5] = {8192, 139264, 401408, 663552, 925696};
__device__ const int cLFIN[5]  = {0, 5, 6, 6, 6};
__device__ const int cLFOUT[5] = {5, 6, 6, 6, 6};
__device__ const int sStart[4] = {0, 469, 657, 728};   // scatter starts for l=1..4

#define PREP_BLOCKS  1269
#define BPACK_TOT    925696
#define BPACK_BLOCKS 3616
#define SCAT_BLOCKS  757
#define CONV0_BLOCKS 2048
#define E0           360000

// ctrl (ints): [0,64) hist | [128,193) bucket_base | [200,265) chunk64 prefix (legacy)
//              [272] total chunk64 | [280,345) pair128 prefix | [352] total pairs

struct BatchPtrs {
    const float* ps[5];
    const int*   dst[5];
    int*   cell[5];
    int*   ctrl[5];
    int*   blkbase[5];
    float* deg[5];
    float* rankf[5];   // reused as posb (int) in-place for l>=1
    int*   dstbase[5];
    int*   eord[5];
};

struct BpackPtrs {
    const float* W[5];
    __bf16* H[5];
    __bf16* M[5];
    __bf16* L[5];
};

// ---------- merged: edge prep (all layers) + W pack ----------
__global__ void prep_bpack(BatchPtrs P, BpackPtrs B)
{
    __shared__ int lh[64];
    int blk = blockIdx.x;
    int t = threadIdx.x;

    if (blk < PREP_BLOCKS) {
        int l = (blk >= 512) + (blk >= 981) + (blk >= 1169) + (blk >= 1240);
        int lb = blk - cStart[l];
        int E = cE[l];
        int stride = cNB[l] * 256;
        const int* dst = P.dst[l];
        float* deg = P.deg[l];
        float* rankf = P.rankf[l];

        if (l == 0) {
            for (int e = lb * 256 + t; e < E; e += stride)
                rankf[e] = atomicAdd(&deg[dst[e]], 1.0f);
            return;
        }
        const float* pseudo = P.ps[l];
        int* cell = P.cell[l];
        if (t < 64) lh[t] = 0;
        __syncthreads();
        for (int e = lb * 256 + t; e < E; e += stride) {
            int b0, b1, b2; float f0, f1, f2;
            basis1(pseudo[e * 3 + 0], b0, f0);
            basis1(pseudo[e * 3 + 1], b1, f1);
            basis1(pseudo[e * 3 + 2], b2, f2);
            int c = b0 + 4 * b1 + 16 * b2;
            cell[e] = c;
            atomicAdd(&lh[c], 1);
            rankf[e] = atomicAdd(&deg[dst[e]], 1.0f);
        }
        __syncthreads();
        if (t < 64) P.blkbase[l][lb * 64 + t] = atomicAdd(&P.ctrl[l][t], lh[t]);
        return;
    }

    // ---- bpack partition ----
    int tt = (blk - PREP_BLOCKS) * 256 + t;
    if (tt >= BPACK_TOT) return;
    int l = (tt >= 8192) + (tt >= 139264) + (tt >= 401408) + (tt >= 663552);
    int tl = tt - (l ? cBTend[l - 1] : 0);
    int lfout = cLFOUT[l], lfin = cLFIN[l];
    int lkb = (l == 0) ? 2 : lfin;
    int fin = 1 << lfin;
    const float* W = B.W[l];
    int o = tl & ((1 << lfout) - 1);
    int kb = (tl >> lfout) & ((1 << lkb) - 1);
    int cellid = tl >> (lfout + lkb);
    int b0 = cellid & 3, b1 = (cellid >> 2) & 3, b2 = cellid >> 4;
    bf16x8 vh, vm, vl;
    #pragma unroll
    for (int j = 0; j < 8; ++j) {
        int r = kb * 8 + j;
        float val = 0.f;
        if (r < (fin << 3)) {
            int c = r >> lfin;
            int i = r & (fin - 1);
            int k = (b0 + (c & 1)) + 5 * (b1 + ((c >> 1) & 1)) + 25 * (b2 + (c >> 2));
            val = W[((((size_t)k << lfin) + i) << lfout) + o];
        }
        __bf16 hv = (__bf16)val;
        vh[j] = hv;
        float r1 = val - (float)hv;
        __bf16 mv = (__bf16)r1;
        vm[j] = mv;
        vl[j] = (__bf16)(r1 - (float)mv);
    }
    *reinterpret_cast<bf16x8*>(B.H[l] + (size_t)tl * 8) = vh;
    *reinterpret_cast<bf16x8*>(B.M[l] + (size_t)tl * 8) = vm;
    *reinterpret_cast<bf16x8*>(B.L[l] + (size_t)tl * 8) = vl;
}

// ---------- batched scans: block l = layer l ----------
__global__ void scan5(BatchPtrs P)
{
    __shared__ int wexc[16];
    __shared__ int tot;
    __shared__ int carry;
    int l = blockIdx.x;
    int* ctrl = P.ctrl[l];
    const float* deg = P.deg[l];
    int* dstbase = P.dstbase[l];
    int N = cN[l];

    int t = (int)threadIdx.x;
    int lane = t & 63;
    int wid = t >> 6;
    if (t == 0) carry = 0;
    if (t < 64) {
        int h = ctrl[t];
        int x = h;
        #pragma unroll
        for (int off = 1; off < 64; off <<= 1) {
            int y = __shfl_up(x, off, 64);
            if (lane >= off) x += y;
        }
        int excl = x - h;
        ctrl[128 + t] = excl;
        int ch = (h + 63) >> 6;
        int cx = ch;
        #pragma unroll
        for (int off = 1; off < 64; off <<= 1) {
            int y = __shfl_up(cx, off, 64);
            if (lane >= off) cx += y;
        }
        ctrl[200 + t] = cx - ch;
        int ph = (h + 127) >> 7;
        int px = ph;
        #pragma unroll
        for (int off = 1; off < 64; off <<= 1) {
            int y = __shfl_up(px, off, 64);
            if (lane >= off) px += y;
        }
        ctrl[280 + t] = px - ph;
        if (t == 63) {
            ctrl[128 + 64] = excl + h;
            ctrl[200 + 64] = cx;
            ctrl[272] = cx;
            ctrl[280 + 64] = px;
            ctrl[352] = px;
        }
    }
    __syncthreads();
    for (int base = 0; base < N; base += 4096) {
        int i0 = base + t * 4;
        int4 v = make_int4(0, 0, 0, 0);
        if (i0 < N) {
            float4 d = *reinterpret_cast<const float4*>(deg + i0);
            v.x = (int)d.x; v.y = (int)d.y; v.z = (int)d.z; v.w = (int)d.w;
        }
        int s = v.x + v.y + v.z + v.w;
        int x = s;
        #pragma unroll
        for (int off = 1; off < 64; off <<= 1) {
            int y = __shfl_up(x, off, 64);
            if (lane >= off) x += y;
        }
        if (lane == 63) wexc[wid] = x;
        __syncthreads();
        if (t < 16) {
            int a = wexc[t];
            int inc = a;
            #pragma unroll
            for (int off = 1; off < 16; off <<= 1) {
                int y = __shfl_up(inc, off, 16);
                if (t >= off) inc += y;
            }
            wexc[t] = inc - a;
            if (t == 15) tot = inc;
        }
        __syncthreads();
        if (i0 < N) {
            int e0 = carry + wexc[wid] + (x - s);
            int4 o;
            o.x = e0;
            o.y = e0 + v.x;
            o.z = o.y + v.y;
            o.w = o.z + v.z;
            *reinterpret_cast<int4*>(dstbase + i0) = o;
        }
        __syncthreads();
        if (t == 0) carry += tot;
        __syncthreads();
    }
    if (t == 0) dstbase[N] = carry;
}

// ---------- merged: scatter (layers 1-4) + conv0 VALU ----------
__global__ void scatter_conv0(BatchPtrs P,
                              const float* __restrict__ x0,
                              const int* __restrict__ src0,
                              const float* __restrict__ ps0,
                              const float* __restrict__ W0,
                              float* __restrict__ msg)
{
    __shared__ int cur[64];
    __shared__ float Wsh[4000];
    int blk = blockIdx.x;
    int t = threadIdx.x;

    if (blk < SCAT_BLOCKS) {
        int li = (blk >= 469) + (blk >= 657) + (blk >= 728);
        int l = 1 + li;
        int lb = blk - sStart[li];
        int E = cE[l];
        int stride = cNB[l] * 256;
        const int* cell = P.cell[l];
        const int* dst = P.dst[l];
        const int* dstbase = P.dstbase[l];
        float* rankf = P.rankf[l];
        int* posb = (int*)rankf;
        int* eord = P.eord[l];

        if (t < 64) cur[t] = P.ctrl[l][128 + t] + P.blkbase[l][lb * 64 + t];
        __syncthreads();
        for (int e = lb * 256 + t; e < E; e += stride) {
            int p = atomicAdd(&cur[cell[e]], 1);
            eord[p] = e;
            int r = (int)rankf[e];
            posb[e] = dstbase[dst[e]] + r;
        }
        return;
    }

    // ---- conv0: exact fp32 rank-1 spline conv, W0 cached in LDS ----
    for (int i = t; i < 4000; i += 256) Wsh[i] = W0[i];
    __syncthreads();
    const int* dst0 = P.dst[0];
    const float* rank0 = P.rankf[0];
    const int* dstb0 = P.dstbase[0];
    int gs = CONV0_BLOCKS * 256;
    for (int g = (blk - SCAT_BLOCKS) * 256 + t; g < E0 * 32; g += gs) {
        int e = g >> 5;
        int o = g & 31;
        int b0, b1, b2; float f0, f1, f2;
        basis1(ps0[e * 3 + 0], b0, f0);
        basis1(ps0[e * 3 + 1], b1, f1);
        basis1(ps0[e * 3 + 2], b2, f2);
        float g0 = 1.f - f0, g1 = 1.f - f1, g2 = 1.f - f2;
        float acc = 0.f;
        #pragma unroll
        for (int c = 0; c < 8; ++c) {
            float bwc = ((c & 1) ? f0 : g0) * (((c >> 1) & 1) ? f1 : g1) * (((c >> 2) & 1) ? f2 : g2);
            int k = (b0 + (c & 1)) + 5 * (b1 + ((c >> 1) & 1)) + 25 * (b2 + (c >> 2));
            acc = fmaf(bwc, Wsh[k * 32 + o], acc);
        }
        int pos = dstb0[dst0[e]] + (int)rank0[e];
        msg[(size_t)pos * 32 + o] = x0[src0[e]] * acc;
    }
}

// ---------- bucketed MFMA conv: 128 edges / 512 threads (8 waves share B staging) ----------
template<int FIN, int FOUT, bool GATHER>
__global__ void conv_mfma(const float* __restrict__ xin,
                          const u64* __restrict__ win,
                          const int* __restrict__ src,
                          const float* __restrict__ pseudo,
                          const __bf16* __restrict__ BpH,
                          const __bf16* __restrict__ BpM,
                          const __bf16* __restrict__ BpL,
                          const int* __restrict__ ctrl,
                          const int* __restrict__ eord,
                          const int* __restrict__ posb,
                          float* __restrict__ msg)
{
    constexpr int KB = FIN;
    constexpr int KSTEPS = FIN / 4;
    constexpr int NF = FOUT / 16;
    constexpr int SLICE = 4 * FOUT * 8;

    __shared__ float cst[128][FOUT + 1];
    __shared__ int posv[128];
    __shared__ __bf16 bsh[3][SLICE];

    int bid = blockIdx.x;
    if (bid >= ctrl[352]) return;
    int blo = 0, bhi = 64;
    while (blo + 1 < bhi) {
        int mid = (blo + bhi) >> 1;
        if (ctrl[280 + mid] <= bid) blo = mid; else bhi = mid;
    }
    int bucket = blo;
    int m0 = (bid - ctrl[280 + bucket]) << 7;
    int bbase = ctrl[128 + bucket];
    int bsize = ctrl[128 + bucket + 1] - bbase;

    int tt = threadIdx.x;           // 512 threads
    int lane = tt & 63;
    int wave = tt >> 6;             // 0..7 -> rows m0+wave*16 .. +16
    int h4 = lane >> 4;
    int col = lane & 15;
    int row = m0 + wave * 16 + col;
    bool valid = row < bsize;
    int e = eord[bbase + (valid ? row : 0)];
    int s = src[e];

    if (tt < 128) {
        int orow = m0 + tt;
        posv[tt] = (orow < bsize) ? posb[eord[bbase + orow]] : -1;
    }

    float bw[8];
    {
        int b0, b1, b2; float f0, f1, f2;
        basis1(pseudo[e * 3 + 0], b0, f0);
        basis1(pseudo[e * 3 + 1], b1, f1);
        basis1(pseudo[e * 3 + 2], b2, f2);
        float g0 = 1.f - f0, g1 = 1.f - f1, g2 = 1.f - f2;
        float vf = valid ? 1.f : 0.f;
        #pragma unroll
        for (int j = 0; j < 8; ++j)
            bw[j] = vf * ((j & 1) ? f0 : g0) * (((j >> 1) & 1) ? f1 : g1) * (((j >> 2) & 1) ? f2 : g2);
    }

    const float* xrow;
    bool xok = true;
    if (GATHER) {
        u64 wv = win[s];
        xok = (wv != 0ull);
        xrow = xin + (size_t)(unsigned int)(wv & 0xffffffffu) * FIN;
    } else {
        xrow = xin + (size_t)s * FIN;
    }

    float xv[8], xw[8];
    #pragma unroll
    for (int j = 0; j < 8; ++j) { xv[j] = 0.f; xw[j] = 0.f; }
    if (xok) {
        const float4* xb = reinterpret_cast<const float4*>(xrow + h4 * 8);
        float4 u0 = xb[0], u1 = xb[1];
        xv[0] = u0.x; xv[1] = u0.y; xv[2] = u0.z; xv[3] = u0.w;
        xv[4] = u1.x; xv[5] = u1.y; xv[6] = u1.z; xv[7] = u1.w;
        if (FIN == 64) {
            const float4* xb2 = reinterpret_cast<const float4*>(xrow + 32 + h4 * 8);
            float4 w0 = xb2[0], w1 = xb2[1];
            xw[0] = w0.x; xw[1] = w0.y; xw[2] = w0.z; xw[3] = w0.w;
            xw[4] = w1.x; xw[5] = w1.y; xw[6] = w1.z; xw[7] = w1.w;
        }
    }

    f32x4 acc[NF];
    #pragma unroll
    for (int nf = 0; nf < NF; ++nf) acc[nf] = (f32x4){0.f, 0.f, 0.f, 0.f};

    for (int kt = 0; kt < KSTEPS; ++kt) {
        __syncthreads();
        {
            size_t gbase = ((size_t)bucket * KB + kt * 4) * FOUT * 8;
            int idx = tt * 8;
            if (idx < SLICE) {
                *reinterpret_cast<bf16x8*>(&bsh[0][idx]) =
                    *reinterpret_cast<const bf16x8*>(BpH + gbase + idx);
                *reinterpret_cast<bf16x8*>(&bsh[1][idx]) =
                    *reinterpret_cast<const bf16x8*>(BpM + gbase + idx);
                *reinterpret_cast<bf16x8*>(&bsh[2][idx]) =
                    *reinterpret_cast<const bf16x8*>(BpL + gbase + idx);
            }
        }
        __syncthreads();

        float v[8];
        if (FIN == 64) {
            float bwc = bw[kt >> 1];
            const float* u = (kt & 1) ? xw : xv;
            #pragma unroll
            for (int j = 0; j < 8; ++j) v[j] = u[j] * bwc;
        } else {
            float bwc = bw[kt];
            #pragma unroll
            for (int j = 0; j < 8; ++j) v[j] = xv[j] * bwc;
        }
        bf16x8 ah, am, al;
        #pragma unroll
        for (int j = 0; j < 8; ++j) {
            __bf16 hv = (__bf16)v[j];
            ah[j] = hv;
            float r1 = v[j] - (float)hv;
            __bf16 mv = (__bf16)r1;
            am[j] = mv;
            al[j] = (__bf16)(r1 - (float)mv);
        }
        #pragma unroll
        for (int nf = 0; nf < NF; ++nf) {
            int loff = (h4 * FOUT + nf * 16 + col) * 8;
            bf16x8 bh = *reinterpret_cast<const bf16x8*>(&bsh[0][loff]);
            bf16x8 bm = *reinterpret_cast<const bf16x8*>(&bsh[1][loff]);
            bf16x8 bl = *reinterpret_cast<const bf16x8*>(&bsh[2][loff]);
            acc[nf] = __builtin_amdgcn_mfma_f32_16x16x32_bf16(ah, bh, acc[nf], 0, 0, 0);
            acc[nf] = __builtin_amdgcn_mfma_f32_16x16x32_bf16(ah, bm, acc[nf], 0, 0, 0);
            acc[nf] = __builtin_amdgcn_mfma_f32_16x16x32_bf16(am, bh, acc[nf], 0, 0, 0);
            acc[nf] = __builtin_amdgcn_mfma_f32_16x16x32_bf16(am, bm, acc[nf], 0, 0, 0);
            acc[nf] = __builtin_amdgcn_mfma_f32_16x16x32_bf16(ah, bl, acc[nf], 0, 0, 0);
            acc[nf] = __builtin_amdgcn_mfma_f32_16x16x32_bf16(al, bh, acc[nf], 0, 0, 0);
        }
    }

    #pragma unroll
    for (int nf = 0; nf < NF; ++nf)
        #pragma unroll
        for (int j = 0; j < 4; ++j)
            cst[wave * 16 + h4 * 4 + j][nf * 16 + col] = acc[nf][j];
    __syncthreads();

    constexpr int F4 = FOUT / 4;
    constexpr int ITER = 128 * F4 / 512;
    #pragma unroll
    for (int i = 0; i < ITER; ++i) {
        int idx = i * 512 + tt;
        int r = idx / F4;
        int c4 = idx - r * F4;
        int p = posv[r];
        if (p >= 0) {
            float4 vq = make_float4(cst[r][c4 * 4], cst[r][c4 * 4 + 1],
                                    cst[r][c4 * 4 + 2], cst[r][c4 * 4 + 3]);
            *reinterpret_cast<float4*>(msg + (size_t)p * FOUT + c4 * 4) = vq;
        }
    }
}

// ---------- finalize: segmented mean + root + bias + act ----------
template<int FIN, int FOUT, int ACT, int POOLMODE, bool GATHER>
__global__ void node_finalize(const float* __restrict__ xin,
                              const u64* __restrict__ winprev,
                              const float* __restrict__ msg,
                              const int* __restrict__ dstbase,
                              const float* __restrict__ deg,
                              const float* __restrict__ root,
                              const float* __restrict__ bias,
                              const float* __restrict__ attw,
                              const float* __restrict__ attb,
                              const int* __restrict__ cluster,
                              float* __restrict__ out,
                              u64* __restrict__ seg64,
                              unsigned int* __restrict__ pooled,
                              int N)
{
    int t = blockIdx.x * blockDim.x + threadIdx.x;
    int n = t / FOUT, o = t % FOUT;
    if (n >= N) return;
    int b0 = dstbase[n];
    int dn = (int)deg[n];
    float a = 0.f;
    for (int r = 0; r < dn; ++r)
        a += msg[(size_t)(b0 + r) * FOUT + o];
    a = a / fmaxf((float)dn, 1.f) + bias[o];

    const float* xrow;
    bool xok = true;
    if (GATHER) {
        u64 wv = winprev[n];
        xok = (wv != 0ull);
        xrow = xin + (size_t)(unsigned int)(wv & 0xffffffffu) * FIN;
    } else {
        xrow = xin + (size_t)n * FIN;
    }
    if (xok) {
        #pragma unroll
        for (int i = 0; i < FIN; ++i)
            a = fmaf(xrow[i], root[i * FOUT + o], a);
    }
    if (ACT == 0) a = (a > 0.f) ? a : expm1f(a);
    else          a = fmaxf(a, 0.f);
    if (POOLMODE == 1) {
        atomicMax(&pooled[(size_t)cluster[n] * FOUT + o], flipf(a));
        return;
    }
    out[t] = a;
    float w = a * attw[2 * o];
    #pragma unroll
    for (int off = FOUT / 2; off >= 1; off >>= 1)
        w += __shfl_xor(w, off, 64);
    if (o == 0) {
        float wt = w + attb[0];
        u64 key = ((u64)flipf(wt) << 32) | (unsigned int)n;
        atomicMax(&seg64[cluster[n]], key);
    }
}

// ---------- fused layer-5 pool_final + FC + log_softmax ----------
__global__ void pool_final_fc(const unsigned int* __restrict__ pooled,
                              const float* __restrict__ fcw,
                              const float* __restrict__ fcb,
                              float* __restrict__ out)
{
    __shared__ float h[8192];
    __shared__ float logits[16][10];
    __shared__ float lse[16];
    int t = threadIdx.x;   // 512
    for (int i = t; i < 8192; i += 512)
        h[i] = pread(pooled[i]);
    __syncthreads();
    if (t < 160) {
        int g = t / 10, cls = t - g * 10;
        float a = fcb[cls];
        for (int j = 0; j < 512; ++j)
            a = fmaf(h[g * 512 + j], fcw[j * 10 + cls], a);
        logits[g][cls] = a;
    }
    __syncthreads();
    if (t < 16) {
        float m = -1e30f;
        for (int c = 0; c < 10; ++c) m = fmaxf(m, logits[t][c]);
        float s = 0.f;
        for (int c = 0; c < 10; ++c) s += expf(logits[t][c] - m);
        lse[t] = m + logf(s);
    }
    __syncthreads();
    if (t < 160) out[t] = logits[t / 10][t - (t / 10) * 10] - lse[t / 10];
}

// ---------- host ----------
static const int hE[5] = {360000, 120000, 48000, 18000, 7200};
static const int hN[5] = {30000, 10000, 4000, 1500, 600};

// ws float offsets
#define OFF_HA     0           // 960000
#define OFF_HB     960000      // 640000
#define OFF_DEG    1600000     // 46112  \.
#define OFF_CTRL   1646112     // 2560    > contiguous zero region
#define OFF_SEG64  1648672     // 32208   |
#define OFF_POOL4  1680880     // 8192   /
#define ZERO_FLTS  89072
#define OFF_BLK    1689072     // 81216
#define OFF_DSTB   1770288     // 46176
#define OFF_CELL   1816464     // 553216
#define OFF_RANK   2369680     // 553216
#define OFF_EORD   2922896     // 553216
#define OFF_BP     3476112     // 11108352
#define OFF_MSG    14584464    // 11520000

static const int cumN_h[5]    = {0, 30000, 40000, 44000, 45500};
static const int cumC_h[5]    = {0, 10000, 14000, 15500, 16100};
static const int cumBLK_h[5]  = {0, 32768, 62784, 74816, 79360};
static const int cumDSTB_h[5] = {0, 30016, 40032, 44048, 45568};
static const int cumE_h[5]    = {0, 360000, 480000, 528000, 546000};
static const size_t planeB_h[5] = {65536, 1048576, 2097152, 2097152, 2097152};
static const size_t cumBPf_h[5] = {0, 98304, 1671168, 4816896, 7962624};

extern "C" void kernel_launch(void* const* d_in, const int* in_sizes, int n_in,
                              void* d_out, int out_size, void* d_ws, size_t ws_size,
                              hipStream_t stream)
{
    const float* x0 = (const float*)d_in[0];
    const int*   src_[5]  = {(const int*)d_in[1], (const int*)d_in[4], (const int*)d_in[7], (const int*)d_in[10], (const int*)d_in[13]};
    const int*   dst_[5]  = {(const int*)d_in[2], (const int*)d_in[5], (const int*)d_in[8], (const int*)d_in[11], (const int*)d_in[14]};
    const float* ps_[5]   = {(const float*)d_in[3], (const float*)d_in[6], (const float*)d_in[9], (const float*)d_in[12], (const float*)d_in[15]};
    const int*   cl_[5]   = {(const int*)d_in[16], (const int*)d_in[17], (const int*)d_in[18], (const int*)d_in[19], (const int*)d_in[20]};
    const float* W_[5]    = {(const float*)d_in[21], (const float*)d_in[24], (const float*)d_in[27], (const float*)d_in[30], (const float*)d_in[33]};
    const float* root_[5] = {(const float*)d_in[22], (const float*)d_in[25], (const float*)d_in[28], (const float*)d_in[31], (const float*)d_in[34]};
    const float* b_[5]    = {(const float*)d_in[23], (const float*)d_in[26], (const float*)d_in[29], (const float*)d_in[32], (const float*)d_in[35]};
    const float* attw_[4] = {(const float*)d_in[36], (const float*)d_in[38], (const float*)d_in[40], (const float*)d_in[42]};
    const float* attb_[4] = {(const float*)d_in[37], (const float*)d_in[39], (const float*)d_in[41], (const float*)d_in[43]};
    const float* fcw = (const float*)d_in[44];
    const float* fcb = (const float*)d_in[45];

    float* ws_f = (float*)d_ws;
    float* hA = ws_f + OFF_HA;
    float* hB = ws_f + OFF_HB;
    float* msg = ws_f + OFF_MSG;
    unsigned int* pool4 = (unsigned int*)(ws_f + OFF_POOL4);

    BatchPtrs P;
    BpackPtrs BP;
    const __bf16* BpH_l[5]; const __bf16* BpM_l[5]; const __bf16* BpL_l[5];
    int* ctrl_l[5]; int* dstb_l[5]; int* eord_l[5]; int* posb_l[5];
    float* deg_l[5];
    u64* seg64_l[5];
    for (int l = 0; l < 5; ++l) {
        P.ps[l] = ps_[l];
        P.dst[l] = dst_[l];
        P.cell[l] = (int*)(ws_f + OFF_CELL + cumE_h[l]);
        P.ctrl[l] = (int*)(ws_f + OFF_CTRL + l * 512);
        P.blkbase[l] = (int*)(ws_f + OFF_BLK + cumBLK_h[l]);
        P.deg[l] = ws_f + OFF_DEG + cumN_h[l];
        P.rankf[l] = ws_f + OFF_RANK + cumE_h[l];
        P.dstbase[l] = (int*)(ws_f + OFF_DSTB + cumDSTB_h[l]);
        P.eord[l] = (int*)(ws_f + OFF_EORD + cumE_h[l]);
        __bf16* H = (__bf16*)(ws_f + OFF_BP + cumBPf_h[l]);
        BP.W[l] = W_[l];
        BP.H[l] = H;
        BP.M[l] = H + planeB_h[l];
        BP.L[l] = H + 2 * planeB_h[l];
        BpH_l[l] = BP.H[l]; BpM_l[l] = BP.M[l]; BpL_l[l] = BP.L[l];
        ctrl_l[l] = P.ctrl[l];
        dstb_l[l] = P.dstbase[l];
        eord_l[l] = P.eord[l];
        posb_l[l] = (int*)P.rankf[l];
        deg_l[l] = P.deg[l];
        seg64_l[l] = (u64*)(ws_f + OFF_SEG64) + cumC_h[l];
    }

    (void)hipMemsetAsync(ws_f + OFF_DEG, 0, (size_t)ZERO_FLTS * 4, stream);
    prep_bpack<<<PREP_BLOCKS + BPACK_BLOCKS, 256, 0, stream>>>(P, BP);
    scan5<<<5, 1024, 0, stream>>>(P);
    scatter_conv0<<<SCAT_BLOCKS + CONV0_BLOCKS, 256, 0, stream>>>(
        P, x0, src_[0], ps_[0], W_[0], msg);

    // layer 0 finalize: x0 -> hA, seg64_0
    node_finalize<1, 32, 0, 0, false><<<(hN[0] * 32) / 256, 256, 0, stream>>>(
        x0, nullptr, msg, dstb_l[0], deg_l[0], root_[0], b_[0], attw_[0], attb_[0], cl_[0], hA, seg64_l[0], nullptr, hN[0]);

    // layer 1: (hA, seg64_0) -> hB, seg64_1
    conv_mfma<32, 64, true><<<hE[1] / 128 + 65, 512, 0, stream>>>(
        hA, seg64_l[0], src_[1], ps_[1], BpH_l[1], BpM_l[1], BpL_l[1], ctrl_l[1], eord_l[1], posb_l[1], msg);
    node_finalize<32, 64, 0, 0, true><<<(hN[1] * 64) / 256, 256, 0, stream>>>(
        hA, seg64_l[0], msg, dstb_l[1], deg_l[1], root_[1], b_[1], attw_[1], attb_[1], cl_[1], hB, seg64_l[1], nullptr, hN[1]);

    // layer 2: (hB, seg64_1) -> hA, seg64_2
    conv_mfma<64, 64, true><<<hE[2] / 128 + 65, 512, 0, stream>>>(
        hB, seg64_l[1], src_[2], ps_[2], BpH_l[2], BpM_l[2], BpL_l[2], ctrl_l[2], eord_l[2], posb_l[2], msg);
    node_finalize<64, 64, 0, 0, true><<<(hN[2] * 64) / 256, 256, 0, stream>>>(
        hB, seg64_l[1], msg, dstb_l[2], deg_l[2], root_[2], b_[2], attw_[2], attb_[2], cl_[2], hA, seg64_l[2], nullptr, hN[2]);

    // layer 3: (hA, seg64_2) -> hB, seg64_3
    conv_mfma<64, 64, true><<<hE[3] / 128 + 65, 512, 0, stream>>>(
        hA, seg64_l[2], src_[3], ps_[3], BpH_l[3], BpM_l[3], BpL_l[3], ctrl_l[3], eord_l[3], posb_l[3], msg);
    node_finalize<64, 64, 0, 0, true><<<(hN[3] * 64) / 256, 256, 0, stream>>>(
        hA, seg64_l[2], msg, dstb_l[3], deg_l[3], root_[3], b_[3], attw_[3], attb_[3], cl_[3], hB, seg64_l[3], nullptr, hN[3]);

    // layer 4: (hB, seg64_3) -> pooled4 (dense pool fused), then FC
    conv_mfma<64, 64, true><<<hE[4] / 128 + 65, 512, 0, stream>>>(
        hB, seg64_l[3], src_[4], ps_[4], BpH_l[4], BpM_l[4], BpL_l[4], ctrl_l[4], eord_l[4], posb_l[4], msg);
    node_finalize<64, 64, 1, 1, true><<<(hN[4] * 64) / 256, 256, 0, stream>>>(
        hB, seg64_l[3], msg, dstb_l[4], deg_l[4], root_[4], b_[4], nullptr, nullptr, cl_[4], nullptr, nullptr, pool4, hN[4]);
    pool_final_fc<<<1, 512, 0, stream>>>(pool4, fcw, fcb, (float*)d_out);
}

// Round 14
// 276.292 us; speedup vs baseline: 1.0219x; 1.0219x over previous
//
#include <hip/hip_runtime.h>
#include <math.h>

#define KS 5

typedef __bf16 bf16x8 __attribute__((ext_vector_type(8)));
typedef float f32x4 __attribute__((ext_vector_type(4)));
typedef unsigned long long u64;

__device__ __forceinline__ unsigned int flipf(float f) {
    unsigned int b = __float_as_uint(f);
    return b ^ ((b >> 31) ? 0xFFFFFFFFu : 0x80000000u);
}
__device__ __forceinline__ float unflipf(unsigned int u) {
    unsigned int b = u ^ ((u >> 31) ? 0x80000000u : 0xFFFFFFFFu);
    return __uint_as_float(b);
}
__device__ __forceinline__ float pread(unsigned int u) {
    return (u == 0u) ? 0.f : unflipf(u);
}

__device__ __forceinline__ void basis1(float p, int& b, float& f) {
    float v = fminf(fmaxf(p, 0.f), 1.f) * (float)(KS - 1);
    float fl = fminf(floorf(v), (float)(KS - 2));
    b = (int)fl; f = v - fl;
}

// ---------- per-layer constants ----------
__device__ const int cE[5]     = {360000, 120000, 48000, 18000, 7200};
__device__ const int cN[5]     = {30000, 10000, 4000, 1500, 600};
__device__ const int cNB[5]    = {512, 469, 188, 71, 29};
__device__ const int cStart[5] = {0, 512, 981, 1169, 1240};
__device__ const int cBTend[5] = {8192, 139264, 401408, 663552, 925696};
__device__ const int cLFIN[5]  = {0, 5, 6, 6, 6};
__device__ const int cLFOUT[5] = {5, 6, 6, 6, 6};
__device__ const int sStart[4] = {0, 469, 657, 728};   // scatter starts for l=1..4

#define PREP_BLOCKS  1269
#define BPACK_TOT    925696
#define BPACK_BLOCKS 3616
#define SCAT_BLOCKS  757
#define CONV0_BLOCKS 2048
#define E0           360000

// ctrl (ints): [0,64) hist | [128,193) bucket_base | [200,265) chunk64 prefix | [272] total chunk64

struct BatchPtrs {
    const float* ps[5];
    const int*   dst[5];
    int*   cell[5];
    int*   ctrl[5];
    int*   blkbase[5];
    float* deg[5];
    float* rankf[5];   // reused as posb (int) in-place for l>=1
    int*   dstbase[5];
    int*   eord[5];
};

struct BpackPtrs {
    const float* W[5];
    __bf16* H[5];
    __bf16* M[5];
    __bf16* L[5];
};

// ---------- merged: edge prep (all layers) + W pack ----------
__global__ void prep_bpack(BatchPtrs P, BpackPtrs B)
{
    __shared__ int lh[64];
    int blk = blockIdx.x;
    int t = threadIdx.x;

    if (blk < PREP_BLOCKS) {
        int l = (blk >= 512) + (blk >= 981) + (blk >= 1169) + (blk >= 1240);
        int lb = blk - cStart[l];
        int E = cE[l];
        int stride = cNB[l] * 256;
        const int* dst = P.dst[l];
        float* deg = P.deg[l];
        float* rankf = P.rankf[l];

        if (l == 0) {
            for (int e = lb * 256 + t; e < E; e += stride)
                rankf[e] = atomicAdd(&deg[dst[e]], 1.0f);
            return;
        }
        const float* pseudo = P.ps[l];
        int* cell = P.cell[l];
        if (t < 64) lh[t] = 0;
        __syncthreads();
        for (int e = lb * 256 + t; e < E; e += stride) {
            int b0, b1, b2; float f0, f1, f2;
            basis1(pseudo[e * 3 + 0], b0, f0);
            basis1(pseudo[e * 3 + 1], b1, f1);
            basis1(pseudo[e * 3 + 2], b2, f2);
            int c = b0 + 4 * b1 + 16 * b2;
            cell[e] = c;
            atomicAdd(&lh[c], 1);
            rankf[e] = atomicAdd(&deg[dst[e]], 1.0f);
        }
        __syncthreads();
        if (t < 64) P.blkbase[l][lb * 64 + t] = atomicAdd(&P.ctrl[l][t], lh[t]);
        return;
    }

    // ---- bpack partition ----
    int tt = (blk - PREP_BLOCKS) * 256 + t;
    if (tt >= BPACK_TOT) return;
    int l = (tt >= 8192) + (tt >= 139264) + (tt >= 401408) + (tt >= 663552);
    int tl = tt - (l ? cBTend[l - 1] : 0);
    int lfout = cLFOUT[l], lfin = cLFIN[l];
    int lkb = (l == 0) ? 2 : lfin;
    int fin = 1 << lfin;
    const float* W = B.W[l];
    int o = tl & ((1 << lfout) - 1);
    int kb = (tl >> lfout) & ((1 << lkb) - 1);
    int cellid = tl >> (lfout + lkb);
    int b0 = cellid & 3, b1 = (cellid >> 2) & 3, b2 = cellid >> 4;
    bf16x8 vh, vm, vl;
    #pragma unroll
    for (int j = 0; j < 8; ++j) {
        int r = kb * 8 + j;
        float val = 0.f;
        if (r < (fin << 3)) {
            int c = r >> lfin;
            int i = r & (fin - 1);
            int k = (b0 + (c & 1)) + 5 * (b1 + ((c >> 1) & 1)) + 25 * (b2 + (c >> 2));
            val = W[((((size_t)k << lfin) + i) << lfout) + o];
        }
        __bf16 hv = (__bf16)val;
        vh[j] = hv;
        float r1 = val - (float)hv;
        __bf16 mv = (__bf16)r1;
        vm[j] = mv;
        vl[j] = (__bf16)(r1 - (float)mv);
    }
    *reinterpret_cast<bf16x8*>(B.H[l] + (size_t)tl * 8) = vh;
    *reinterpret_cast<bf16x8*>(B.M[l] + (size_t)tl * 8) = vm;
    *reinterpret_cast<bf16x8*>(B.L[l] + (size_t)tl * 8) = vl;
}

// ---------- batched scans (2-barrier): block l = layer l ----------
__global__ void scan5(BatchPtrs P)
{
    __shared__ int wtot[128];
    __shared__ int tots;
    int l = blockIdx.x;
    int* ctrl = P.ctrl[l];
    const float* deg = P.deg[l];
    int* dstbase = P.dstbase[l];
    int N = cN[l];

    int t = (int)threadIdx.x;
    int lane = t & 63;
    int wid = t >> 6;

    // 64-bucket scans (wave 0)
    if (t < 64) {
        int h = ctrl[t];
        int x = h;
        #pragma unroll
        for (int off = 1; off < 64; off <<= 1) {
            int y = __shfl_up(x, off, 64);
            if (lane >= off) x += y;
        }
        int excl = x - h;
        ctrl[128 + t] = excl;
        int ch = (h + 63) >> 6;
        int cx = ch;
        #pragma unroll
        for (int off = 1; off < 64; off <<= 1) {
            int y = __shfl_up(cx, off, 64);
            if (lane >= off) cx += y;
        }
        ctrl[200 + t] = cx - ch;
        if (t == 63) {
            ctrl[128 + 64] = excl + h;
            ctrl[200 + 64] = cx;
            ctrl[272] = cx;
        }
    }

    // deg scan: load all <=8 chunks into registers (static unroll), per-wave scans
    int4 v0, v1, v2, v3, v4, v5, v6, v7;
    int ss[8], xs[8];
    #define LOADC(c, vr) { \
        int i0 = (c << 12) + t * 4; \
        vr = make_int4(0, 0, 0, 0); \
        if (i0 < N) { \
            float4 d = *reinterpret_cast<const float4*>(deg + i0); \
            vr.x = (int)d.x; vr.y = (int)d.y; vr.z = (int)d.z; vr.w = (int)d.w; \
        } \
        int s = vr.x + vr.y + vr.z + vr.w; \
        int x = s; \
        _Pragma("unroll") \
        for (int off = 1; off < 64; off <<= 1) { \
            int y = __shfl_up(x, off, 64); \
            if (lane >= off) x += y; \
        } \
        ss[c] = s; xs[c] = x; \
        if (lane == 63) wtot[c * 16 + wid] = x; \
    }
    LOADC(0, v0) LOADC(1, v1) LOADC(2, v2) LOADC(3, v3)
    LOADC(4, v4) LOADC(5, v5) LOADC(6, v6) LOADC(7, v7)
    #undef LOADC
    __syncthreads();
    if (t < 64) {
        int a0 = wtot[2 * t], a1 = wtot[2 * t + 1];
        int p = a0 + a1;
        int pi = p;
        #pragma unroll
        for (int off = 1; off < 64; off <<= 1) {
            int y = __shfl_up(pi, off, 64);
            if (lane >= off) pi += y;
        }
        int excl = pi - p;
        wtot[2 * t] = excl;
        wtot[2 * t + 1] = excl + a0;
        if (t == 63) tots = pi;
    }
    __syncthreads();
    #define STOREC(c, vr) { \
        int i0 = (c << 12) + t * 4; \
        if (i0 < N) { \
            int e0 = wtot[c * 16 + wid] + (xs[c] - ss[c]); \
            int4 o; \
            o.x = e0; \
            o.y = e0 + vr.x; \
            o.z = o.y + vr.y; \
            o.w = o.z + vr.z; \
            *reinterpret_cast<int4*>(dstbase + i0) = o; \
        } \
    }
    STOREC(0, v0) STOREC(1, v1) STOREC(2, v2) STOREC(3, v3)
    STOREC(4, v4) STOREC(5, v5) STOREC(6, v6) STOREC(7, v7)
    #undef STOREC
    if (t == 0) dstbase[N] = tots;
}

// ---------- merged: scatter (layers 1-4) + conv0 VALU ----------
__global__ void scatter_conv0(BatchPtrs P,
                              const float* __restrict__ x0,
                              const int* __restrict__ src0,
                              const float* __restrict__ ps0,
                              const float* __restrict__ W0,
                              float* __restrict__ msg)
{
    __shared__ int cur[64];
    __shared__ float Wsh[4000];
    int blk = blockIdx.x;
    int t = threadIdx.x;

    if (blk < SCAT_BLOCKS) {
        int li = (blk >= 469) + (blk >= 657) + (blk >= 728);
        int l = 1 + li;
        int lb = blk - sStart[li];
        int E = cE[l];
        int stride = cNB[l] * 256;
        const int* cell = P.cell[l];
        const int* dst = P.dst[l];
        const int* dstbase = P.dstbase[l];
        float* rankf = P.rankf[l];
        int* posb = (int*)rankf;
        int* eord = P.eord[l];

        if (t < 64) cur[t] = P.ctrl[l][128 + t] + P.blkbase[l][lb * 64 + t];
        __syncthreads();
        for (int e = lb * 256 + t; e < E; e += stride) {
            int p = atomicAdd(&cur[cell[e]], 1);
            eord[p] = e;
            int r = (int)rankf[e];
            posb[e] = dstbase[dst[e]] + r;
        }
        return;
    }

    // ---- conv0: exact fp32 rank-1 spline conv, W0 cached in LDS ----
    for (int i = t; i < 4000; i += 256) Wsh[i] = W0[i];
    __syncthreads();
    const int* dst0 = P.dst[0];
    const float* rank0 = P.rankf[0];
    const int* dstb0 = P.dstbase[0];
    int gs = CONV0_BLOCKS * 256;
    for (int g = (blk - SCAT_BLOCKS) * 256 + t; g < E0 * 32; g += gs) {
        int e = g >> 5;
        int o = g & 31;
        int b0, b1, b2; float f0, f1, f2;
        basis1(ps0[e * 3 + 0], b0, f0);
        basis1(ps0[e * 3 + 1], b1, f1);
        basis1(ps0[e * 3 + 2], b2, f2);
        float g0 = 1.f - f0, g1 = 1.f - f1, g2 = 1.f - f2;
        float acc = 0.f;
        #pragma unroll
        for (int c = 0; c < 8; ++c) {
            float bwc = ((c & 1) ? f0 : g0) * (((c >> 1) & 1) ? f1 : g1) * (((c >> 2) & 1) ? f2 : g2);
            int k = (b0 + (c & 1)) + 5 * (b1 + ((c >> 1) & 1)) + 25 * (b2 + (c >> 2));
            acc = fmaf(bwc, Wsh[k * 32 + o], acc);
        }
        int pos = dstb0[dst0[e]] + (int)rank0[e];
        msg[(size_t)pos * 32 + o] = x0[src0[e]] * acc;
    }
}

// ---------- bucketed MFMA conv: 64 edges / 256 threads ----------
template<int FIN, int FOUT, bool GATHER>
__global__ void conv_mfma(const float* __restrict__ xin,
                          const u64* __restrict__ win,
                          const int* __restrict__ src,
                          const float* __restrict__ pseudo,
                          const __bf16* __restrict__ BpH,
                          const __bf16* __restrict__ BpM,
                          const __bf16* __restrict__ BpL,
                          const int* __restrict__ ctrl,
                          const int* __restrict__ eord,
                          const int* __restrict__ posb,
                          float* __restrict__ msg)
{
    constexpr int KB = FIN;
    constexpr int KSTEPS = FIN / 4;
    constexpr int NF = FOUT / 16;
    constexpr int SLICE = 4 * FOUT * 8;

    __shared__ float cst[64][FOUT + 1];
    __shared__ int posv[64];
    __shared__ __bf16 bsh[3][SLICE];

    int bid = blockIdx.x;
    if (bid >= ctrl[272]) return;
    int blo = 0, bhi = 64;
    while (blo + 1 < bhi) {
        int mid = (blo + bhi) >> 1;
        if (ctrl[200 + mid] <= bid) blo = mid; else bhi = mid;
    }
    int bucket = blo;
    int m0 = (bid - ctrl[200 + bucket]) << 6;
    int bbase = ctrl[128 + bucket];
    int bsize = ctrl[128 + bucket + 1] - bbase;

    int tt = threadIdx.x;
    int lane = tt & 63;
    int wave = tt >> 6;
    int h4 = lane >> 4;
    int col = lane & 15;
    int row = m0 + wave * 16 + col;
    bool valid = row < bsize;
    int e = eord[bbase + (valid ? row : 0)];
    int s = src[e];

    if (tt < 64) {
        int orow = m0 + tt;
        posv[tt] = (orow < bsize) ? posb[eord[bbase + orow]] : -1;
    }

    float bw[8];
    {
        int b0, b1, b2; float f0, f1, f2;
        basis1(pseudo[e * 3 + 0], b0, f0);
        basis1(pseudo[e * 3 + 1], b1, f1);
        basis1(pseudo[e * 3 + 2], b2, f2);
        float g0 = 1.f - f0, g1 = 1.f - f1, g2 = 1.f - f2;
        float vf = valid ? 1.f : 0.f;
        #pragma unroll
        for (int j = 0; j < 8; ++j)
            bw[j] = vf * ((j & 1) ? f0 : g0) * (((j >> 1) & 1) ? f1 : g1) * (((j >> 2) & 1) ? f2 : g2);
    }

    const float* xrow;
    bool xok = true;
    if (GATHER) {
        u64 wv = win[s];
        xok = (wv != 0ull);
        xrow = xin + (size_t)(unsigned int)(wv & 0xffffffffu) * FIN;
    } else {
        xrow = xin + (size_t)s * FIN;
    }

    float xv[8], xw[8];
    #pragma unroll
    for (int j = 0; j < 8; ++j) { xv[j] = 0.f; xw[j] = 0.f; }
    if (xok) {
        const float4* xb = reinterpret_cast<const float4*>(xrow + h4 * 8);
        float4 u0 = xb[0], u1 = xb[1];
        xv[0] = u0.x; xv[1] = u0.y; xv[2] = u0.z; xv[3] = u0.w;
        xv[4] = u1.x; xv[5] = u1.y; xv[6] = u1.z; xv[7] = u1.w;
        if (FIN == 64) {
            const float4* xb2 = reinterpret_cast<const float4*>(xrow + 32 + h4 * 8);
            float4 w0 = xb2[0], w1 = xb2[1];
            xw[0] = w0.x; xw[1] = w0.y; xw[2] = w0.z; xw[3] = w0.w;
            xw[4] = w1.x; xw[5] = w1.y; xw[6] = w1.z; xw[7] = w1.w;
        }
    }

    f32x4 acc[NF];
    #pragma unroll
    for (int nf = 0; nf < NF; ++nf) acc[nf] = (f32x4){0.f, 0.f, 0.f, 0.f};

    for (int kt = 0; kt < KSTEPS; ++kt) {
        __syncthreads();
        {
            size_t gbase = ((size_t)bucket * KB + kt * 4) * FOUT * 8;
            int idx = tt * 8;
            if (idx < SLICE) {
                *reinterpret_cast<bf16x8*>(&bsh[0][idx]) =
                    *reinterpret_cast<const bf16x8*>(BpH + gbase + idx);
                *reinterpret_cast<bf16x8*>(&bsh[1][idx]) =
                    *reinterpret_cast<const bf16x8*>(BpM + gbase + idx);
                *reinterpret_cast<bf16x8*>(&bsh[2][idx]) =
                    *reinterpret_cast<const bf16x8*>(BpL + gbase + idx);
            }
        }
        __syncthreads();

        float v[8];
        if (FIN == 64) {
            float bwc = bw[kt >> 1];
            const float* u = (kt & 1) ? xw : xv;
            #pragma unroll
            for (int j = 0; j < 8; ++j) v[j] = u[j] * bwc;
        } else {
            float bwc = bw[kt];
            #pragma unroll
            for (int j = 0; j < 8; ++j) v[j] = xv[j] * bwc;
        }
        bf16x8 ah, am, al;
        #pragma unroll
        for (int j = 0; j < 8; ++j) {
            __bf16 hv = (__bf16)v[j];
            ah[j] = hv;
            float r1 = v[j] - (float)hv;
            __bf16 mv = (__bf16)r1;
            am[j] = mv;
            al[j] = (__bf16)(r1 - (float)mv);
        }
        #pragma unroll
        for (int nf = 0; nf < NF; ++nf) {
            int loff = (h4 * FOUT + nf * 16 + col) * 8;
            bf16x8 bh = *reinterpret_cast<const bf16x8*>(&bsh[0][loff]);
            bf16x8 bm = *reinterpret_cast<const bf16x8*>(&bsh[1][loff]);
            bf16x8 bl = *reinterpret_cast<const bf16x8*>(&bsh[2][loff]);
            acc[nf] = __builtin_amdgcn_mfma_f32_16x16x32_bf16(ah, bh, acc[nf], 0, 0, 0);
            acc[nf] = __builtin_amdgcn_mfma_f32_16x16x32_bf16(ah, bm, acc[nf], 0, 0, 0);
            acc[nf] = __builtin_amdgcn_mfma_f32_16x16x32_bf16(am, bh, acc[nf], 0, 0, 0);
            acc[nf] = __builtin_amdgcn_mfma_f32_16x16x32_bf16(am, bm, acc[nf], 0, 0, 0);
            acc[nf] = __builtin_amdgcn_mfma_f32_16x16x32_bf16(ah, bl, acc[nf], 0, 0, 0);
            acc[nf] = __builtin_amdgcn_mfma_f32_16x16x32_bf16(al, bh, acc[nf], 0, 0, 0);
        }
    }

    #pragma unroll
    for (int nf = 0; nf < NF; ++nf)
        #pragma unroll
        for (int j = 0; j < 4; ++j)
            cst[wave * 16 + h4 * 4 + j][nf * 16 + col] = acc[nf][j];
    __syncthreads();

    constexpr int F4 = FOUT / 4;
    constexpr int ITER = 64 * F4 / 256;
    #pragma unroll
    for (int i = 0; i < ITER; ++i) {
        int idx = i * 256 + tt;
        int r = idx / F4;
        int c4 = idx - r * F4;
        int p = posv[r];
        if (p >= 0) {
            float4 vq = make_float4(cst[r][c4 * 4], cst[r][c4 * 4 + 1],
                                    cst[r][c4 * 4 + 2], cst[r][c4 * 4 + 3]);
            *reinterpret_cast<float4*>(msg + (size_t)p * FOUT + c4 * 4) = vq;
        }
    }
}

// ---------- finalize: segmented mean + root + bias + act ----------
template<int FIN, int FOUT, int ACT, int POOLMODE, bool GATHER>
__global__ void node_finalize(const float* __restrict__ xin,
                              const u64* __restrict__ winprev,
                              const float* __restrict__ msg,
                              const int* __restrict__ dstbase,
                              const float* __restrict__ deg,
                              const float* __restrict__ root,
                              const float* __restrict__ bias,
                              const float* __restrict__ attw,
                              const float* __restrict__ attb,
                              const int* __restrict__ cluster,
                              float* __restrict__ out,
                              u64* __restrict__ seg64,
                              unsigned int* __restrict__ pooled,
                              int N)
{
    int t = blockIdx.x * blockDim.x + threadIdx.x;
    int n = t / FOUT, o = t % FOUT;
    if (n >= N) return;
    int b0 = dstbase[n];
    int dn = (int)deg[n];
    float a = 0.f;
    for (int r = 0; r < dn; ++r)
        a += msg[(size_t)(b0 + r) * FOUT + o];
    a = a / fmaxf((float)dn, 1.f) + bias[o];

    const float* xrow;
    bool xok = true;
    if (GATHER) {
        u64 wv = winprev[n];
        xok = (wv != 0ull);
        xrow = xin + (size_t)(unsigned int)(wv & 0xffffffffu) * FIN;
    } else {
        xrow = xin + (size_t)n * FIN;
    }
    if (xok) {
        #pragma unroll
        for (int i = 0; i < FIN; ++i)
            a = fmaf(xrow[i], root[i * FOUT + o], a);
    }
    if (ACT == 0) a = (a > 0.f) ? a : expm1f(a);
    else          a = fmaxf(a, 0.f);
    if (POOLMODE == 1) {
        atomicMax(&pooled[(size_t)cluster[n] * FOUT + o], flipf(a));
        return;
    }
    out[t] = a;
    float w = a * attw[2 * o];
    #pragma unroll
    for (int off = FOUT / 2; off >= 1; off >>= 1)
        w += __shfl_xor(w, off, 64);
    if (o == 0) {
        float wt = w + attb[0];
        u64 key = ((u64)flipf(wt) << 32) | (unsigned int)n;
        atomicMax(&seg64[cluster[n]], key);
    }
}

// ---------- fused layer-5 pool_final + FC + log_softmax ----------
__global__ void pool_final_fc(const unsigned int* __restrict__ pooled,
                              const float* __restrict__ fcw,
                              const float* __restrict__ fcb,
                              float* __restrict__ out)
{
    __shared__ float h[8192];
    __shared__ float logits[16][10];
    __shared__ float lse[16];
    int t = threadIdx.x;   // 512
    for (int i = t; i < 8192; i += 512)
        h[i] = pread(pooled[i]);
    __syncthreads();
    if (t < 160) {
        int g = t / 10, cls = t - g * 10;
        float a = fcb[cls];
        for (int j = 0; j < 512; ++j)
            a = fmaf(h[g * 512 + j], fcw[j * 10 + cls], a);
        logits[g][cls] = a;
    }
    __syncthreads();
    if (t < 16) {
        float m = -1e30f;
        for (int c = 0; c < 10; ++c) m = fmaxf(m, logits[t][c]);
        float s = 0.f;
        for (int c = 0; c < 10; ++c) s += expf(logits[t][c] - m);
        lse[t] = m + logf(s);
    }
    __syncthreads();
    if (t < 160) out[t] = logits[t / 10][t - (t / 10) * 10] - lse[t / 10];
}

// ---------- host ----------
static const int hE[5] = {360000, 120000, 48000, 18000, 7200};
static const int hN[5] = {30000, 10000, 4000, 1500, 600};

// ws float offsets
#define OFF_HA     0           // 960000
#define OFF_HB     960000      // 640000
#define OFF_DEG    1600000     // 46112  \.
#define OFF_CTRL   1646112     // 2560    > contiguous zero region
#define OFF_SEG64  1648672     // 32208   |
#define OFF_POOL4  1680880     // 8192   /
#define ZERO_FLTS  89072
#define OFF_BLK    1689072     // 81216
#define OFF_DSTB   1770288     // 46176
#define OFF_CELL   1816464     // 553216
#define OFF_RANK   2369680     // 553216
#define OFF_EORD   2922896     // 553216
#define OFF_BP     3476112     // 11108352
#define OFF_MSG    14584464    // 11520000

static const int cumN_h[5]    = {0, 30000, 40000, 44000, 45500};
static const int cumC_h[5]    = {0, 10000, 14000, 15500, 16100};
static const int cumBLK_h[5]  = {0, 32768, 62784, 74816, 79360};
static const int cumDSTB_h[5] = {0, 30016, 40032, 44048, 45568};
static const int cumE_h[5]    = {0, 360000, 480000, 528000, 546000};
static const size_t planeB_h[5] = {65536, 1048576, 2097152, 2097152, 2097152};
static const size_t cumBPf_h[5] = {0, 98304, 1671168, 4816896, 7962624};

extern "C" void kernel_launch(void* const* d_in, const int* in_sizes, int n_in,
                              void* d_out, int out_size, void* d_ws, size_t ws_size,
                              hipStream_t stream)
{
    const float* x0 = (const float*)d_in[0];
    const int*   src_[5]  = {(const int*)d_in[1], (const int*)d_in[4], (const int*)d_in[7], (const int*)d_in[10], (const int*)d_in[13]};
    const int*   dst_[5]  = {(const int*)d_in[2], (const int*)d_in[5], (const int*)d_in[8], (const int*)d_in[11], (const int*)d_in[14]};
    const float* ps_[5]   = {(const float*)d_in[3], (const float*)d_in[6], (const float*)d_in[9], (const float*)d_in[12], (const float*)d_in[15]};
    const int*   cl_[5]   = {(const int*)d_in[16], (const int*)d_in[17], (const int*)d_in[18], (const int*)d_in[19], (const int*)d_in[20]};
    const float* W_[5]    = {(const float*)d_in[21], (const float*)d_in[24], (const float*)d_in[27], (const float*)d_in[30], (const float*)d_in[33]};
    const float* root_[5] = {(const float*)d_in[22], (const float*)d_in[25], (const float*)d_in[28], (const float*)d_in[31], (const float*)d_in[34]};
    const float* b_[5]    = {(const float*)d_in[23], (const float*)d_in[26], (const float*)d_in[29], (const float*)d_in[32], (const float*)d_in[35]};
    const float* attw_[4] = {(const float*)d_in[36], (const float*)d_in[38], (const float*)d_in[40], (const float*)d_in[42]};
    const float* attb_[4] = {(const float*)d_in[37], (const float*)d_in[39], (const float*)d_in[41], (const float*)d_in[43]};
    const float* fcw = (const float*)d_in[44];
    const float* fcb = (const float*)d_in[45];

    float* ws_f = (float*)d_ws;
    float* hA = ws_f + OFF_HA;
    float* hB = ws_f + OFF_HB;
    float* msg = ws_f + OFF_MSG;
    unsigned int* pool4 = (unsigned int*)(ws_f + OFF_POOL4);

    BatchPtrs P;
    BpackPtrs BP;
    const __bf16* BpH_l[5]; const __bf16* BpM_l[5]; const __bf16* BpL_l[5];
    int* ctrl_l[5]; int* dstb_l[5]; int* eord_l[5]; int* posb_l[5];
    float* deg_l[5];
    u64* seg64_l[5];
    for (int l = 0; l < 5; ++l) {
        P.ps[l] = ps_[l];
        P.dst[l] = dst_[l];
        P.cell[l] = (int*)(ws_f + OFF_CELL + cumE_h[l]);
        P.ctrl[l] = (int*)(ws_f + OFF_CTRL + l * 512);
        P.blkbase[l] = (int*)(ws_f + OFF_BLK + cumBLK_h[l]);
        P.deg[l] = ws_f + OFF_DEG + cumN_h[l];
        P.rankf[l] = ws_f + OFF_RANK + cumE_h[l];
        P.dstbase[l] = (int*)(ws_f + OFF_DSTB + cumDSTB_h[l]);
        P.eord[l] = (int*)(ws_f + OFF_EORD + cumE_h[l]);
        __bf16* H = (__bf16*)(ws_f + OFF_BP + cumBPf_h[l]);
        BP.W[l] = W_[l];
        BP.H[l] = H;
        BP.M[l] = H + planeB_h[l];
        BP.L[l] = H + 2 * planeB_h[l];
        BpH_l[l] = BP.H[l]; BpM_l[l] = BP.M[l]; BpL_l[l] = BP.L[l];
        ctrl_l[l] = P.ctrl[l];
        dstb_l[l] = P.dstbase[l];
        eord_l[l] = P.eord[l];
        posb_l[l] = (int*)P.rankf[l];
        deg_l[l] = P.deg[l];
        seg64_l[l] = (u64*)(ws_f + OFF_SEG64) + cumC_h[l];
    }

    (void)hipMemsetAsync(ws_f + OFF_DEG, 0, (size_t)ZERO_FLTS * 4, stream);
    prep_bpack<<<PREP_BLOCKS + BPACK_BLOCKS, 256, 0, stream>>>(P, BP);
    scan5<<<5, 1024, 0, stream>>>(P);
    scatter_conv0<<<SCAT_BLOCKS + CONV0_BLOCKS, 256, 0, stream>>>(
        P, x0, src_[0], ps_[0], W_[0], msg);

    // layer 0 finalize: x0 -> hA, seg64_0
    node_finalize<1, 32, 0, 0, false><<<(hN[0] * 32) / 256, 256, 0, stream>>>(
        x0, nullptr, msg, dstb_l[0], deg_l[0], root_[0], b_[0], attw_[0], attb_[0], cl_[0], hA, seg64_l[0], nullptr, hN[0]);

    // layer 1: (hA, seg64_0) -> hB, seg64_1
    conv_mfma<32, 64, true><<<hE[1] / 64 + 65, 256, 0, stream>>>(
        hA, seg64_l[0], src_[1], ps_[1], BpH_l[1], BpM_l[1], BpL_l[1], ctrl_l[1], eord_l[1], posb_l[1], msg);
    node_finalize<32, 64, 0, 0, true><<<(hN[1] * 64) / 256, 256, 0, stream>>>(
        hA, seg64_l[0], msg, dstb_l[1], deg_l[1], root_[1], b_[1], attw_[1], attb_[1], cl_[1], hB, seg64_l[1], nullptr, hN[1]);

    // layer 2: (hB, seg64_1) -> hA, seg64_2
    conv_mfma<64, 64, true><<<hE[2] / 64 + 65, 256, 0, stream>>>(
        hB, seg64_l[1], src_[2], ps_[2], BpH_l[2], BpM_l[2], BpL_l[2], ctrl_l[2], eord_l[2], posb_l[2], msg);
    node_finalize<64, 64, 0, 0, true><<<(hN[2] * 64) / 256, 256, 0, stream>>>(
        hB, seg64_l[1], msg, dstb_l[2], deg_l[2], root_[2], b_[2], attw_[2], attb_[2], cl_[2], hA, seg64_l[2], nullptr, hN[2]);

    // layer 3: (hA, seg64_2) -> hB, seg64_3
    conv_mfma<64, 64, true><<<hE[3] / 64 + 65, 256, 0, stream>>>(
        hA, seg64_l[2], src_[3], ps_[3], BpH_l[3], BpM_l[3], BpL_l[3], ctrl_l[3], eord_l[3], posb_l[3], msg);
    node_finalize<64, 64, 0, 0, true><<<(hN[3] * 64) / 256, 256, 0, stream>>>(
        hA, seg64_l[2], msg, dstb_l[3], deg_l[3], root_[3], b_[3], attw_[3], attb_[3], cl_[3], hB, seg64_l[3], nullptr, hN[3]);

    // layer 4: (hB, seg64_3) -> pooled4 (dense pool fused), then FC
    conv_mfma<64, 64, true><<<hE[4] / 64 + 65, 256, 0, stream>>>(
        hB, seg64_l[3], src_[4], ps_[4], BpH_l[4], BpM_l[4], BpL_l[4], ctrl_l[4], eord_l[4], posb_l[4], msg);
    node_finalize<64, 64, 1, 1, true><<<(hN[4] * 64) / 256, 256, 0, stream>>>(
        hB, seg64_l[3], msg, dstb_l[4], deg_l[4], root_[4], b_[4], nullptr, nullptr, cl_[4], nullptr, nullptr, pool4, hN[4]);
    pool_final_fc<<<1, 512, 0, stream>>>(pool4, fcw, fcb, (float*)d_out);
}